// Round 7
// baseline (493.373 us; speedup 1.0000x reference)
//
#include <hip/hip_runtime.h>

// LSTM: B=2048, T=2048 serial, H=16, IN=1.
// R7 layout: lane = (batch-row, hidden-unit). 4 batches per wave (rows of 16
// lanes), 512 waves total. Each lane computes ALL FOUR gates of unit j of its
// batch -> no cross-lane gate gather at all (R2-R6's 4x ds_bpermute, ~120cyc
// on the recurrence chain, eliminated). Matvec: 4 gate accumulators x 16
// row-local rotations via fused v_fmac_f32_dpp row_ror:s (one wave64 instr
// serves all 4 batches). x scalar per batch-row via ds_swizzle row-broadcast,
// hoisted off the chain. Folds: weights/bias pre-scaled by -log2e (sigmoid
// gates) / -2log2e (g): sigma = rcp(1+exp2(acc)) with NO affine; c kept
// scaled by -2log2e so tanh's exp2 takes c directly.

__device__ __forceinline__ float i2f(int i) { return __int_as_float(i); }
__device__ __forceinline__ int   f2i(float f) { return __float_as_int(f); }

#define LOG2E 1.44269504088896340736f

// Fused rotate+FMA: acc += h[(j +- n) & 15] * w   (one VALU instruction)
#define FMAC_DPP(acc, h_, w_, n)                                               \
    asm("v_fmac_f32_dpp %0, %1, %2 row_ror:" #n " row_mask:0xf bank_mask:0xf"  \
        : "+v"(acc) : "v"(h_), "v"(w_));

#define ROT4(s)                                                              \
    FMAC_DPP(a0_, h, w0[s], s) FMAC_DPP(a1_, h, w1[s], s)                    \
    FMAC_DPP(a2_, h, w2[s], s) FMAC_DPP(a3_, h, w3[s], s)

// ds_swizzle BitMode: src_lane = ((lane & 0x10) | K)  -> row-local broadcast
// of the lane holding x[t0+K] for this 16-lane row (within each 32-half).
#define STEP(K) {                                                            \
    float xc_ = i2f(__builtin_amdgcn_ds_swizzle(f2i(xblk),                   \
                                                (((K) << 5) | 0x10)));       \
    float a0_ = fmaf(wi0, xc_, bs0);                                         \
    float a1_ = fmaf(wi1, xc_, bs1);                                         \
    float a2_ = fmaf(wi2, xc_, bs2);                                         \
    float a3_ = fmaf(wi3, xc_, bs3);                                         \
    a0_ = fmaf(h, w0[0], a0_);                                               \
    a1_ = fmaf(h, w1[0], a1_);                                               \
    a2_ = fmaf(h, w2[0], a2_);                                               \
    a3_ = fmaf(h, w3[0], a3_);                                               \
    ROT4(1)  ROT4(2)  ROT4(3)  ROT4(4)  ROT4(5)  ROT4(6)  ROT4(7)            \
    ROT4(8)  ROT4(9)  ROT4(10) ROT4(11) ROT4(12) ROT4(13) ROT4(14) ROT4(15)  \
    float e0_  = __builtin_amdgcn_exp2f(a0_);                                \
    float e1_  = __builtin_amdgcn_exp2f(a1_);                                \
    float e2_  = __builtin_amdgcn_exp2f(a2_);                                \
    float e3_  = __builtin_amdgcn_exp2f(a3_);                                \
    float ri_  = __builtin_amdgcn_rcpf(1.0f + e0_);   /* sigma(i) */         \
    float rf_  = __builtin_amdgcn_rcpf(1.0f + e1_);   /* sigma(f) */         \
    float rg_  = __builtin_amdgcn_rcpf(1.0f + e2_);                          \
    float ro_  = __builtin_amdgcn_rcpf(1.0f + e3_);   /* sigma(o) */         \
    float gs_  = fmaf(-4.0f * LOG2E, rg_, 2.0f * LOG2E); /* -2log2e*tanh */  \
    c = fmaf(rf_, c, ri_ * gs_);              /* c scaled by -2log2e */      \
    float ec_  = __builtin_amdgcn_exp2f(c);                                  \
    float rc_  = __builtin_amdgcn_rcpf(1.0f + ec_);                          \
    float o2_  = ro_ + ro_;                   /* off-chain */                \
    h = fmaf(o2_, rc_, -ro_);                 /* o * tanh(c) */              \
}

__global__ __launch_bounds__(64, 1)
__attribute__((amdgpu_waves_per_eu(1)))
void lstm_fused(
    const float* __restrict__ x,
    const float* __restrict__ Wih,
    const float* __restrict__ Whh,
    const float* __restrict__ bih,
    const float* __restrict__ bhh,
    const float* __restrict__ Wfc,
    const float* __restrict__ bfc,
    float* __restrict__ out)
{
    const int T   = 2048;
    const int l   = threadIdx.x;         // 0..63, one wave per block
    const int row = l >> 4;              // batch sub-index 0..3
    const int j   = l & 15;              // hidden unit
    const int b   = blockIdx.x * 4 + row;

    // Probe DPP row_ror direction: after ror:1, lane l holds j from lane (l+-1)&15.
    int probe = __builtin_amdgcn_mov_dpp(j, 0x121, 0xF, 0xF, true);
    const int dir = (probe == ((j + 1) & 15)) ? 1 : -1;

    // Pre-rotated, pre-scaled weights: w_q[s] pairs with row_ror:s of h.
    // Gate order (PyTorch): q=0:i, 1:f, 2:g(tanh), 3:o. Scales: -log2e for
    // sigmoid gates, -2log2e for g.
    const int r0 = (0  + j) * 16, r1 = (16 + j) * 16,
              r2 = (32 + j) * 16, r3 = (48 + j) * 16;
    float w0[16], w1[16], w2[16], w3[16];
#pragma unroll
    for (int s = 0; s < 16; ++s) {
        int k = (j + s * dir + 32) & 15;
        w0[s] = Whh[r0 + k] * (-LOG2E);
        w1[s] = Whh[r1 + k] * (-LOG2E);
        w2[s] = Whh[r2 + k] * (-2.0f * LOG2E);
        w3[s] = Whh[r3 + k] * (-LOG2E);
    }
    const float wi0 = Wih[ 0 + j] * (-LOG2E);
    const float wi1 = Wih[16 + j] * (-LOG2E);
    const float wi2 = Wih[32 + j] * (-2.0f * LOG2E);
    const float wi3 = Wih[48 + j] * (-LOG2E);
    const float bs0 = (bih[ 0 + j] + bhh[ 0 + j]) * (-LOG2E);
    const float bs1 = (bih[16 + j] + bhh[16 + j]) * (-LOG2E);
    const float bs2 = (bih[32 + j] + bhh[32 + j]) * (-2.0f * LOG2E);
    const float bs3 = (bih[48 + j] + bhh[48 + j]) * (-LOG2E);

    const float* xp = x + (size_t)b * T;  // this lane's batch sequence
    float xblk = xp[j];                   // 16 timesteps staged per block
    float h = 0.0f, c = 0.0f;             // c holds -2log2e * c_real

#pragma unroll 1
    for (int blk = 0; blk < 128; ++blk) {
        const int nxt = (blk < 127) ? blk + 1 : 127;
        float xn = xp[nxt * 16 + j];      // prefetch next 16 steps
        STEP(0)  STEP(1)  STEP(2)  STEP(3)
        STEP(4)  STEP(5)  STEP(6)  STEP(7)
        STEP(8)  STEP(9)  STEP(10) STEP(11)
        STEP(12) STEP(13) STEP(14) STEP(15)
        xblk = xn;
    }

    // out[b] = sum_j Wfc[j]*h[j] + bfc : row-local 16-lane reduction
    float p = h * Wfc[j];
    p += __shfl_xor(p, 1);
    p += __shfl_xor(p, 2);
    p += __shfl_xor(p, 4);
    p += __shfl_xor(p, 8);
    if (j == 0) out[b] = p + bfc[0];
}

extern "C" void kernel_launch(void* const* d_in, const int* in_sizes, int n_in,
                              void* d_out, int out_size, void* d_ws, size_t ws_size,
                              hipStream_t stream) {
    const float* x   = (const float*)d_in[0];
    const float* Wih = (const float*)d_in[1];
    const float* Whh = (const float*)d_in[2];
    const float* bih = (const float*)d_in[3];
    const float* bhh = (const float*)d_in[4];
    const float* Wfc = (const float*)d_in[5];
    const float* bfc = (const float*)d_in[6];
    float* out = (float*)d_out;

    const int B = 2048;
    const int threads = 64;          // one wave per block
    const int blocks  = B / 4;       // 4 batches per wave -> 512 blocks
    hipLaunchKernelGGL(lstm_fused, dim3(blocks), dim3(threads), 0, stream,
                       x, Wih, Whh, bih, bhh, Wfc, bfc, out);
}